// Round 19
// baseline (267.404 us; speedup 1.0000x reference)
//
#include <hip/hip_runtime.h>

// ---------------------------------------------------------------------------
// Types / helpers
// ---------------------------------------------------------------------------
typedef __bf16 bf16x8 __attribute__((ext_vector_type(8)));
typedef float  f32x4  __attribute__((ext_vector_type(4)));
typedef unsigned short ushort8 __attribute__((ext_vector_type(8)));

__device__ __forceinline__ unsigned short f2bf(float f) {
    unsigned u = __float_as_uint(f);
    u += 0x7FFFu + ((u >> 16) & 1u);   // round-to-nearest-even
    return (unsigned short)(u >> 16);
}

__device__ __forceinline__ f32x4 mfma16x16x32(bf16x8 a, bf16x8 b, f32x4 c) {
    return __builtin_amdgcn_mfma_f32_16x16x32_bf16(a, b, c, 0, 0, 0);
}

__device__ __forceinline__ bf16x8 ld8(const unsigned short* p) {
    return __builtin_bit_cast(bf16x8, *(const ushort8*)p);
}

// raw v_exp_f32 (exp2). Very negative input flushes to zero.
__device__ __forceinline__ float exp2_fast(float x) {
    float r; asm("v_exp_f32 %0, %1" : "=v"(r) : "v"(x)); return r;
}

// async global->LDS, 16B per lane. LDS dest = wave-uniform base + lane*16.
__device__ __forceinline__ void glds16(const unsigned short* g, unsigned short* l) {
    __builtin_amdgcn_global_load_lds(
        (const __attribute__((address_space(1))) void*)g,
        (__attribute__((address_space(3))) void*)l, 16, 0, 0);
}

__device__ __forceinline__ float gelu_tanh(float x) {
    const float c = 0.7978845608028654f;
    float z = c * (x + 0.044715f * x * x * x);
    float e = __expf(2.f * z);
    float th = 1.f - 2.f / (e + 1.f);   // tanh(z)
    return 0.5f * x * (1.f + th);
}

#define N_EMBD 768
#define SEQ    1024
#define NHEAD  12
#define HS     64
#define MROWS  8192           // B*T

// ---------------------------------------------------------------------------
// Transpose + cast fp32 [K,N] -> bf16 [N,K]
// ---------------------------------------------------------------------------
__global__ __launch_bounds__(256) void tcast_kernel(const float* __restrict__ in,
                                                    unsigned short* __restrict__ out,
                                                    int K, int N) {
    __shared__ float tile[32][33];
    int nb = blockIdx.x * 32, kb = blockIdx.y * 32;
    int tx = threadIdx.x, ty = threadIdx.y;   // 32 x 8
#pragma unroll
    for (int i = 0; i < 4; i++) {
        int k = kb + ty + i * 8;
        tile[ty + i * 8][tx] = in[(size_t)k * N + nb + tx];
    }
    __syncthreads();
#pragma unroll
    for (int i = 0; i < 4; i++) {
        int n = nb + ty + i * 8;
        out[(size_t)n * K + kb + tx] = f2bf(tile[tx][ty + i * 8]);
    }
}

// ---------------------------------------------------------------------------
// LayerNorm fp32 row -> bf16 row. ONE WAVE per row (no LDS, no barriers).
// ---------------------------------------------------------------------------
__global__ __launch_bounds__(256) void ln_kernel(const float* __restrict__ x,
                                                 const float* __restrict__ g,
                                                 const float* __restrict__ b,
                                                 unsigned short* __restrict__ out) {
    const int row = blockIdx.x * 4 + (threadIdx.x >> 6);
    const int lane = threadIdx.x & 63;
    const float* xr = x + (size_t)row * N_EMBD;
    float v[12], s = 0.f, s2 = 0.f;
#pragma unroll
    for (int i = 0; i < 12; i++) {
        v[i] = xr[lane + i * 64];
        s += v[i]; s2 += v[i] * v[i];
    }
#pragma unroll
    for (int m = 1; m < 64; m <<= 1) { s += __shfl_xor(s, m); s2 += __shfl_xor(s2, m); }
    float mu  = s * (1.f / N_EMBD);
    float var = s2 * (1.f / N_EMBD) - mu * mu;
    float inv = rsqrtf(var + 1e-5f);
#pragma unroll
    for (int i = 0; i < 12; i++) {
        int c = lane + i * 64;
        out[(size_t)row * N_EMBD + c] = f2bf((v[i] - mu) * inv * g[c] + b[c]);
    }
}

// ---------------------------------------------------------------------------
// GEMM, BK=32 high-occupancy variant of the proven 2-phase skeleton:
// C = A @ B^T + bias. EPI 0: bf16 ; EPI 1: gelu->bf16 ; EPI 2: f32 +res.
// Tile (WM*32)x128, BK=32, 4 waves (2x2), double-buffered LDS, ONE barrier
// per K-step, pointer-bumped glds16 staging. LDS 32KB (WM=4) / 24KB (WM=2)
// -> 5-6 blocks/CU (vs 2-3 at BK=64): the counters show nothing saturated
// (MFMA 23%, LDS ~25%, HBM 21%) => latency-bound; more co-resident blocks
// overlap the per-K-step dependency chain. Same FLOP/LDS-byte ratio.
// Swizzle for 64B rows: 16B-chunk c' = c ^ ((row>>1)&3) both sides
// (8 distinct slots per 16-lane group, 2-way = free). XCD remap.
// ---------------------------------------------------------------------------
template <int EPI, int WM>
__global__ __launch_bounds__(256) void gemm_bt_kernel(
    const unsigned short* __restrict__ A, const unsigned short* __restrict__ BT,
    const float* __restrict__ bias, const float* __restrict__ res,
    float* __restrict__ outF, unsigned short* __restrict__ outB,
    int M, int N, int K) {
    constexpr int BM = WM * 32;
    constexpr int AI = WM / 2;           // A staging instrs (64 rows each)
    constexpr int ASZ = BM * 32;         // ushorts per A buffer
    constexpr int BSZ = 128 * 32;        // ushorts per B buffer
    __shared__ __attribute__((aligned(16))) unsigned short As[2 * ASZ];
    __shared__ __attribute__((aligned(16))) unsigned short Bs[2 * BSZ];
    const int gx = gridDim.x;
    const int slot = blockIdx.y * gx + blockIdx.x;
    const int chunk = (gx * gridDim.y) >> 3;
    const int logical = (slot & 7) * chunk + (slot >> 3);
    const int m0 = (logical / gx) * BM, n0 = (logical % gx) * 128;
    const int t = threadIdx.x, lane = t & 63, wid = t >> 6;
    const int wr = wid >> 1, wc = wid & 1;

    f32x4 acc[WM][4] = {};

    const int rrow = lane & 15, g = lane >> 4;
    const int swz = (rrow >> 1) & 3;        // read-side XOR (16B-chunk units)

    // staging: chunk n = i*256 + t; row = n>>2 = i*64 + (t>>2); stored
    // col-chunk (t&3) holds source col-chunk (t&3) ^ ((row>>1)&3);
    // (row>>1)&3 == (t>>3)&3 (i*64>>1 = i*32 == 0 mod 4).
    const int srow = t >> 2;
    const int scol = ((t & 3) ^ ((t >> 3) & 3)) * 8;

    const int NT = K >> 5;

    const unsigned short* aP[AI];
    const unsigned short* bP[2];
#pragma unroll
    for (int i = 0; i < AI; i++) aP[i] = &A[(size_t)(m0 + i * 64 + srow) * K + scol];
#pragma unroll
    for (int i = 0; i < 2; i++)  bP[i] = &BT[(size_t)(n0 + i * 64 + srow) * K + scol];

    auto stage = [&](int buf) {
#pragma unroll
        for (int i = 0; i < AI; i++) {
            glds16(aP[i], &As[buf * ASZ + i * 2048 + wid * 512]);
            aP[i] += 32;
        }
#pragma unroll
        for (int i = 0; i < 2; i++) {
            glds16(bP[i], &Bs[buf * BSZ + i * 2048 + wid * 512]);
            bP[i] += 32;
        }
    };

    stage(0);
    __syncthreads();

    int cur = 0;
    for (int kt = 0; kt < NT; ++kt) {
        if (kt + 1 < NT) stage(cur ^ 1);
        const unsigned short* ab = &As[cur * ASZ];
        const unsigned short* bb = &Bs[cur * BSZ];
        bf16x8 af[WM], bfr[4];
#pragma unroll
        for (int i = 0; i < WM; i++) {
            int row = wr * (WM * 16) + i * 16 + rrow;
            af[i] = ld8(&ab[row * 32 + ((g ^ swz) << 3)]);
        }
#pragma unroll
        for (int j = 0; j < 4; j++) {
            int row = wc * 64 + j * 16 + rrow;
            bfr[j] = ld8(&bb[row * 32 + ((g ^ swz) << 3)]);
        }
#pragma unroll
        for (int i = 0; i < WM; i++)
#pragma unroll
            for (int j = 0; j < 4; j++) acc[i][j] = mfma16x16x32(af[i], bfr[j], acc[i][j]);
        __syncthreads();   // drains vmcnt (next tile's DMA, issued pre-compute)
        cur ^= 1;
    }

    const int crow = g * 4, ccol = rrow;
#pragma unroll
    for (int i = 0; i < WM; i++) {
        int gr0 = m0 + wr * (WM * 16) + i * 16 + crow;
#pragma unroll
        for (int j = 0; j < 4; j++) {
            int gc = n0 + wc * 64 + j * 16 + ccol;
            float bv = bias[gc];
#pragma unroll
            for (int r = 0; r < 4; r++) {
                int gr = gr0 + r;
                float v = acc[i][j][r] + bv;
                if constexpr (EPI == 1) v = gelu_tanh(v);
                if constexpr (EPI == 2) {
                    outF[(size_t)gr * N + gc] = v + res[(size_t)gr * N + gc];
                } else {
                    outB[(size_t)gr * N + gc] = f2bf(v);
                }
            }
        }
    }
}

// ---------------------------------------------------------------------------
// Causal flash attention v4 (round-16 proven): KVBLK=128 staging, paired
// q-tiles, static-max softmax, MFMA row-sum, T5 setprio. LDS 45KB.
// ---------------------------------------------------------------------------
#define SCALE_LOG2E 0.18033688011112042f   // 0.125 * log2(e)

__global__ __launch_bounds__(256, 3) void attn_kernel(const unsigned short* __restrict__ qkv,
                                                      unsigned short* __restrict__ yb) {
    const int slot = blockIdx.y * 8 + blockIdx.x;
    const int logical = (slot & 7) * 96 + (slot >> 3);
    const int p = logical & 7;
    const int bh = logical >> 3;
    const int b = bh / NHEAD, h = bh % NHEAD;
    const int t = threadIdx.x, lane = t & 63, wid = t >> 6;
    const int q0A = p * 64 + wid * 16, q0B = (15 - p) * 64 + wid * 16;
    const int ntA = p + 1, ntB = 16 - p;          // ntA < ntB always
    const int ntT = (ntB + 1) >> 1;               // 128-row staging steps
    const int rrow = lane & 15, g = lane >> 4, kg8 = g * 8;

    __shared__ __attribute__((aligned(16))) unsigned short Ks[128 * 64];   // [kv][d]
    __shared__ __attribute__((aligned(16))) unsigned short Vt[64 * 152];   // [d][kv+pad]
    __shared__ __attribute__((aligned(16))) unsigned short Ps[4][16 * 80];

    bf16x8 qfA[2], qfB[2];
    {
        size_t baseA = ((size_t)(b * SEQ + q0A + rrow)) * 2304 + h * HS;
        qfA[0] = ld8(&qkv[baseA + kg8]);
        qfA[1] = ld8(&qkv[baseA + 32 + kg8]);
        size_t baseB = ((size_t)(b * SEQ + q0B + rrow)) * 2304 + h * HS;
        qfB[0] = ld8(&qkv[baseB + kg8]);
        qfB[1] = ld8(&qkv[baseB + 32 + kg8]);
    }

    f32x4 yA[4] = {}, yB[4] = {};
    float lA[4] = {0.f, 0.f, 0.f, 0.f}, lB[4] = {0.f, 0.f, 0.f, 0.f};

    const int kr = t >> 3;
    const int kc = ((t & 7) ^ (kr & 7)) * 8;
    const int vd = t & 63, vk = (t >> 6) * 32;

    unsigned short* P = &Ps[wid][0];
    const bf16x8 vones = __builtin_bit_cast(bf16x8,
        (ushort8){0x3F80, 0x3F80, 0x3F80, 0x3F80, 0x3F80, 0x3F80, 0x3F80, 0x3F80});
    const int sw = (rrow & 7) << 3;

    for (int tt = 0; tt < ntT; tt++) {
        const int kv0 = tt * 128;
        __syncthreads();   // previous tile's LDS reads complete
#pragma unroll
        for (int i = 0; i < 4; i++)
            glds16(&qkv[((size_t)(b * SEQ + kv0 + i * 32 + kr)) * 2304 + 768 + h * HS + kc],
                   &Ks[i * 2048 + wid * 512]);
#pragma unroll
        for (int iv = 0; iv < 4; iv++) {
            ushort8 v8;
#pragma unroll
            for (int i = 0; i < 8; i++)
                v8[i] = qkv[((size_t)(b * SEQ + kv0 + vk + iv * 8 + i)) * 2304 + 1536 + h * HS + vd];
            *(ushort8*)&Vt[vd * 152 + vk + iv * 8] = v8;
        }
        __syncthreads();   // staging visible (drains vmcnt + lgkmcnt)

#pragma unroll
        for (int hh = 0; hh < 2; hh++) {
            const int sidx = tt * 2 + hh;
            if (sidx >= ntB) continue;            // block-uniform
            const bool doA = (sidx < ntA);
            const bool maskB = (sidx == ntB - 1), maskA = (sidx == ntA - 1);
            const int kvs = kv0 + hh * 64;

            f32x4 sB[4], sA[4];
#pragma unroll
            for (int ct = 0; ct < 4; ct++) {
                const int j = ct * 16 + rrow;
                const unsigned short* krow = &Ks[(hh * 64 + j) * 64];
                bf16x8 k0 = ld8(&krow[((g    ) ^ (j & 7)) * 8]);
                bf16x8 k1 = ld8(&krow[((g + 4) ^ (j & 7)) * 8]);
                f32x4 zB = {};
                zB = mfma16x16x32(qfB[0], k0, zB);
                zB = mfma16x16x32(qfB[1], k1, zB);
                sB[ct] = zB;
                if (doA) {
                    f32x4 zA = {};
                    zA = mfma16x16x32(qfA[0], k0, zA);
                    zA = mfma16x16x32(qfA[1], k1, zA);
                    sA[ct] = zA;
                }
            }

            const int qrbB = q0B + g * 4;
#pragma unroll
            for (int ct = 0; ct < 4; ct++) {
                const int j = ct * 16 + rrow, jj = kvs + j;
#pragma unroll
                for (int r = 0; r < 4; r++) {
                    float v = sB[ct][r] * SCALE_LOG2E;
                    if (maskB && jj > qrbB + r) v = -1e30f;
                    const int q = g * 4 + r;
                    P[q * 80 + (j ^ ((q & 7) << 3))] = f2bf(exp2_fast(v));
                }
            }
            asm volatile("s_waitcnt lgkmcnt(0)" ::: "memory");
            __builtin_amdgcn_sched_barrier(0);
            {
                bf16x8 pa0 = ld8(&P[rrow * 80 + ((kg8     ) ^ sw)]);
                bf16x8 pa1 = ld8(&P[rrow * 80 + ((kg8 + 32) ^ sw)]);
                __builtin_amdgcn_s_setprio(1);
                f32x4 ss = {};
                ss = mfma16x16x32(pa0, vones, ss);
                ss = mfma16x16x32(pa1, vones, ss);
#pragma unroll
                for (int r = 0; r < 4; r++) lB[r] += ss[r];
#pragma unroll
                for (int dt = 0; dt < 4; dt++) {
                    const unsigned short* vr = &Vt[(dt * 16 + rrow) * 152 + hh * 64];
                    yB[dt] = mfma16x16x32(pa0, ld8(&vr[kg8     ]), yB[dt]);
                    yB[dt] = mfma16x16x32(pa1, ld8(&vr[kg8 + 32]), yB[dt]);
                }
                __builtin_amdgcn_s_setprio(0);
            }

            if (doA) {
                const int qrbA = q0A + g * 4;
#pragma unroll
                for (int ct = 0; ct < 4; ct++) {
                    const int j = ct * 16 + rrow, jj = kvs + j;
#pragma unroll
                    for (int r = 0; r < 4; r++) {
                        float v = sA[ct][r] * SCALE_LOG2E;
                        if (maskA && jj > qrbA + r) v = -1e30f;
                        const int q = g * 4 + r;
                        P[q * 80 + (j ^ ((q & 7) << 3))] = f2bf(exp2_fast(v));
                    }
                }
                asm volatile("s_waitcnt lgkmcnt(0)" ::: "memory");
                __builtin_amdgcn_sched_barrier(0);
                bf16x8 pa0 = ld8(&P[rrow * 80 + ((kg8     ) ^ sw)]);
                bf16x8 pa1 = ld8(&P[rrow * 80 + ((kg8 + 32) ^ sw)]);
                __builtin_amdgcn_s_setprio(1);
                f32x4 ss = {};
                ss = mfma16x16x32(pa0, vones, ss);
                ss = mfma16x16x32(pa1, vones, ss);
#pragma unroll
                for (int r = 0; r < 4; r++) lA[r] += ss[r];
#pragma unroll
                for (int dt = 0; dt < 4; dt++) {
                    const unsigned short* vr = &Vt[(dt * 16 + rrow) * 152 + hh * 64];
                    yA[dt] = mfma16x16x32(pa0, ld8(&vr[kg8     ]), yA[dt]);
                    yA[dt] = mfma16x16x32(pa1, ld8(&vr[kg8 + 32]), yA[dt]);
                }
                __builtin_amdgcn_s_setprio(0);
            }
        }
    }

#pragma unroll
    for (int dt = 0; dt < 4; dt++)
#pragma unroll
        for (int r = 0; r < 4; r++) {
            int col = h * HS + dt * 16 + rrow;
            yb[((size_t)(b * SEQ + q0B + g * 4 + r)) * N_EMBD + col] = f2bf(yB[dt][r] / lB[r]);
            yb[((size_t)(b * SEQ + q0A + g * 4 + r)) * N_EMBD + col] = f2bf(yA[dt][r] / lA[r]);
        }
}

// ---------------------------------------------------------------------------
// Orchestration
// ---------------------------------------------------------------------------
extern "C" void kernel_launch(void* const* d_in, const int* in_sizes, int n_in,
                              void* d_out, int out_size, void* d_ws, size_t ws_size,
                              hipStream_t stream) {
    const float* x        = (const float*)d_in[0];
    const float* ln1_g    = (const float*)d_in[1];
    const float* ln1_b    = (const float*)d_in[2];
    const float* w_attn   = (const float*)d_in[3];
    const float* b_attn   = (const float*)d_in[4];
    const float* w_proj   = (const float*)d_in[5];
    const float* b_proj   = (const float*)d_in[6];
    const float* ln2_g    = (const float*)d_in[7];
    const float* ln2_b    = (const float*)d_in[8];
    const float* w_fc     = (const float*)d_in[9];
    const float* b_fc     = (const float*)d_in[10];
    const float* w_fcp    = (const float*)d_in[11];
    const float* b_fcp    = (const float*)d_in[12];
    float* out = (float*)d_out;

    // workspace carve (ushort elements)
    unsigned short* ws = (unsigned short*)d_ws;
    unsigned short* wT_attn = ws;                          // 2304*768
    unsigned short* wT_proj = wT_attn + 2304 * 768;        // 768*768
    unsigned short* wT_fc   = wT_proj + 768 * 768;         // 3072*768
    unsigned short* wT_fcp  = wT_fc   + 3072 * 768;        // 768*3072
    unsigned short* xb      = wT_fcp  + 768 * 3072;        // 8192*768
    unsigned short* qkv     = xb      + (size_t)MROWS * 768;   // 8192*2304
    unsigned short* yb      = qkv     + (size_t)MROWS * 2304;  // 8192*768
    unsigned short* act     = qkv;    // 8192*3072 overlays qkv+yb (dead then)
    float* x2 = (float*)(yb + (size_t)MROWS * 768);        // 8192*768 fp32

    dim3 tb(32, 8);
    tcast_kernel<<<dim3(2304 / 32, 768 / 32), tb, 0, stream>>>(w_attn, wT_attn, 768, 2304);
    tcast_kernel<<<dim3(768 / 32, 768 / 32),  tb, 0, stream>>>(w_proj, wT_proj, 768, 768);
    tcast_kernel<<<dim3(3072 / 32, 768 / 32), tb, 0, stream>>>(w_fc,   wT_fc,   768, 3072);
    tcast_kernel<<<dim3(768 / 32, 3072 / 32), tb, 0, stream>>>(w_fcp,  wT_fcp,  3072, 768);

    // ln1 (wave-per-row)
    ln_kernel<<<MROWS / 4, 256, 0, stream>>>(x, ln1_g, ln1_b, xb);
    // qkv = ln1(x) @ w_attn + b_attn
    gemm_bt_kernel<0, 4><<<dim3(2304 / 128, MROWS / 128), 256, 0, stream>>>(
        xb, wT_attn, b_attn, nullptr, nullptr, qkv, MROWS, 2304, 768);
    // attention (paired q-tiles, KVBLK=128 staging)
    attn_kernel<<<dim3(8, 96), 256, 0, stream>>>(qkv, yb);
    // x2 = attn_y @ w_proj + b_proj + x
    gemm_bt_kernel<2, 2><<<dim3(768 / 128, MROWS / 64), 256, 0, stream>>>(
        yb, wT_proj, b_proj, x, x2, nullptr, MROWS, 768, 768);
    // ln2 (wave-per-row)
    ln_kernel<<<MROWS / 4, 256, 0, stream>>>(x2, ln2_g, ln2_b, xb);
    // act = gelu(h2 @ w_fc + b_fc)
    gemm_bt_kernel<1, 4><<<dim3(3072 / 128, MROWS / 128), 256, 0, stream>>>(
        xb, wT_fc, b_fc, nullptr, nullptr, act, MROWS, 3072, 768);
    // out = act @ w_fc_proj + b_fc_proj + x2
    gemm_bt_kernel<2, 2><<<dim3(768 / 128, MROWS / 64), 256, 0, stream>>>(
        act, wT_fcp, b_fcp, x2, out, nullptr, MROWS, 768, 3072);
}

// Round 20
// 242.016 us; speedup vs baseline: 1.1049x; 1.1049x over previous
//
#include <hip/hip_runtime.h>

// ---------------------------------------------------------------------------
// Types / helpers
// ---------------------------------------------------------------------------
typedef __bf16 bf16x8 __attribute__((ext_vector_type(8)));
typedef float  f32x4  __attribute__((ext_vector_type(4)));
typedef unsigned short ushort8 __attribute__((ext_vector_type(8)));

__device__ __forceinline__ unsigned short f2bf(float f) {
    unsigned u = __float_as_uint(f);
    u += 0x7FFFu + ((u >> 16) & 1u);   // round-to-nearest-even
    return (unsigned short)(u >> 16);
}

__device__ __forceinline__ f32x4 mfma16x16x32(bf16x8 a, bf16x8 b, f32x4 c) {
    return __builtin_amdgcn_mfma_f32_16x16x32_bf16(a, b, c, 0, 0, 0);
}

__device__ __forceinline__ bf16x8 ld8(const unsigned short* p) {
    return __builtin_bit_cast(bf16x8, *(const ushort8*)p);
}

// raw v_exp_f32 (exp2). Very negative input flushes to zero.
__device__ __forceinline__ float exp2_fast(float x) {
    float r; asm("v_exp_f32 %0, %1" : "=v"(r) : "v"(x)); return r;
}

// async global->LDS, 16B per lane. LDS dest = wave-uniform base + lane*16.
__device__ __forceinline__ void glds16(const unsigned short* g, unsigned short* l) {
    __builtin_amdgcn_global_load_lds(
        (const __attribute__((address_space(1))) void*)g,
        (__attribute__((address_space(3))) void*)l, 16, 0, 0);
}

__device__ __forceinline__ float gelu_tanh(float x) {
    const float c = 0.7978845608028654f;
    float z = c * (x + 0.044715f * x * x * x);
    float e = __expf(2.f * z);
    float th = 1.f - 2.f / (e + 1.f);   // tanh(z)
    return 0.5f * x * (1.f + th);
}

#define N_EMBD 768
#define SEQ    1024
#define NHEAD  12
#define HS     64
#define MROWS  8192           // B*T

// ---------------------------------------------------------------------------
// Transpose + cast fp32 [K,N] -> bf16 [N,K]
// ---------------------------------------------------------------------------
__global__ __launch_bounds__(256) void tcast_kernel(const float* __restrict__ in,
                                                    unsigned short* __restrict__ out,
                                                    int K, int N) {
    __shared__ float tile[32][33];
    int nb = blockIdx.x * 32, kb = blockIdx.y * 32;
    int tx = threadIdx.x, ty = threadIdx.y;   // 32 x 8
#pragma unroll
    for (int i = 0; i < 4; i++) {
        int k = kb + ty + i * 8;
        tile[ty + i * 8][tx] = in[(size_t)k * N + nb + tx];
    }
    __syncthreads();
#pragma unroll
    for (int i = 0; i < 4; i++) {
        int n = nb + ty + i * 8;
        out[(size_t)n * K + kb + tx] = f2bf(tile[tx][ty + i * 8]);
    }
}

// ---------------------------------------------------------------------------
// LayerNorm fp32 row -> bf16 row. ONE WAVE per row (no LDS, no barriers).
// ---------------------------------------------------------------------------
__global__ __launch_bounds__(256) void ln_kernel(const float* __restrict__ x,
                                                 const float* __restrict__ g,
                                                 const float* __restrict__ b,
                                                 unsigned short* __restrict__ out) {
    const int row = blockIdx.x * 4 + (threadIdx.x >> 6);
    const int lane = threadIdx.x & 63;
    const float* xr = x + (size_t)row * N_EMBD;
    float v[12], s = 0.f, s2 = 0.f;
#pragma unroll
    for (int i = 0; i < 12; i++) {
        v[i] = xr[lane + i * 64];
        s += v[i]; s2 += v[i] * v[i];
    }
#pragma unroll
    for (int m = 1; m < 64; m <<= 1) { s += __shfl_xor(s, m); s2 += __shfl_xor(s2, m); }
    float mu  = s * (1.f / N_EMBD);
    float var = s2 * (1.f / N_EMBD) - mu * mu;
    float inv = rsqrtf(var + 1e-5f);
#pragma unroll
    for (int i = 0; i < 12; i++) {
        int c = lane + i * 64;
        out[(size_t)row * N_EMBD + c] = f2bf((v[i] - mu) * inv * g[c] + b[c]);
    }
}

// ---------------------------------------------------------------------------
// GEMM (round-14/16 proven): C = A @ B^T + bias, epilogue.
// EPI 0: out bf16 ; EPI 1: gelu->bf16 ; EPI 2: out f32 = acc+bias+res.
// Tile (WM*32)x128, BK=64, 4 waves (2x2). 2-phase double-buffer, one barrier
// per K-step, pointer-bumped glds16 staging. XOR swizzle both-sides; XCD remap.
// ---------------------------------------------------------------------------
template <int EPI, int WM>
__global__ __launch_bounds__(256) void gemm_bt_kernel(
    const unsigned short* __restrict__ A, const unsigned short* __restrict__ BT,
    const float* __restrict__ bias, const float* __restrict__ res,
    float* __restrict__ outF, unsigned short* __restrict__ outB,
    int M, int N, int K) {
    constexpr int BM = WM * 32;
    constexpr int ASZ = BM * 64;
    constexpr int BSZ = 128 * 64;
    __shared__ __attribute__((aligned(16))) unsigned short As[2 * ASZ];
    __shared__ __attribute__((aligned(16))) unsigned short Bs[2 * BSZ];
    const int gx = gridDim.x;
    const int slot = blockIdx.y * gx + blockIdx.x;
    const int chunk = (gx * gridDim.y) >> 3;
    const int logical = (slot & 7) * chunk + (slot >> 3);
    const int m0 = (logical / gx) * BM, n0 = (logical % gx) * 128;
    const int t = threadIdx.x, lane = t & 63, wid = t >> 6;
    const int wr = wid >> 1, wc = wid & 1;

    f32x4 acc[WM][4] = {};

    const int rrow = lane & 15, g = lane >> 4;
    const int swz8 = (rrow & 7) << 3;

    const int srow = t >> 3;
    const int scol = ((t & 7) ^ (srow & 7)) * 8;

    const int NT = K >> 6;

    const unsigned short* aP[WM];
    const unsigned short* bP[4];
#pragma unroll
    for (int i = 0; i < WM; i++) aP[i] = &A[(size_t)(m0 + i * 32 + srow) * K + scol];
#pragma unroll
    for (int i = 0; i < 4; i++)  bP[i] = &BT[(size_t)(n0 + i * 32 + srow) * K + scol];

    auto stage = [&](int buf) {
#pragma unroll
        for (int i = 0; i < WM; i++) {
            glds16(aP[i], &As[buf * ASZ + i * 2048 + wid * 512]);
            aP[i] += 64;
        }
#pragma unroll
        for (int i = 0; i < 4; i++) {
            glds16(bP[i], &Bs[buf * BSZ + i * 2048 + wid * 512]);
            bP[i] += 64;
        }
    };

    stage(0);
    __syncthreads();

    int cur = 0;
    for (int kt = 0; kt < NT; ++kt) {
        if (kt + 1 < NT) stage(cur ^ 1);
        const unsigned short* ab = &As[cur * ASZ];
        const unsigned short* bb = &Bs[cur * BSZ];
#pragma unroll
        for (int s = 0; s < 2; s++) {
            bf16x8 af[WM], bfr[4];
#pragma unroll
            for (int i = 0; i < WM; i++) {
                int row = wr * (WM * 16) + i * 16 + rrow;
                af[i] = ld8(&ab[row * 64 + ((((s << 2) | g) << 3) ^ swz8)]);
            }
#pragma unroll
            for (int j = 0; j < 4; j++) {
                int row = wc * 64 + j * 16 + rrow;
                bfr[j] = ld8(&bb[row * 64 + ((((s << 2) | g) << 3) ^ swz8)]);
            }
#pragma unroll
            for (int i = 0; i < WM; i++)
#pragma unroll
                for (int j = 0; j < 4; j++) acc[i][j] = mfma16x16x32(af[i], bfr[j], acc[i][j]);
        }
        __syncthreads();   // drains vmcnt (next tile's DMA, issued pre-compute)
        cur ^= 1;
    }

    const int crow = g * 4, ccol = rrow;
#pragma unroll
    for (int i = 0; i < WM; i++) {
        int gr0 = m0 + wr * (WM * 16) + i * 16 + crow;
#pragma unroll
        for (int j = 0; j < 4; j++) {
            int gc = n0 + wc * 64 + j * 16 + ccol;
            float bv = bias[gc];
#pragma unroll
            for (int r = 0; r < 4; r++) {
                int gr = gr0 + r;
                float v = acc[i][j][r] + bv;
                if constexpr (EPI == 1) v = gelu_tanh(v);
                if constexpr (EPI == 2) {
                    outF[(size_t)gr * N + gc] = v + res[(size_t)gr * N + gc];
                } else {
                    outB[(size_t)gr * N + gc] = f2bf(v);
                }
            }
        }
    }
}

// ---------------------------------------------------------------------------
// Causal flash attention v4 (round-16 proven): KVBLK=128 staging, paired
// q-tiles, static-max softmax, MFMA row-sum, T5 setprio. LDS 45KB.
// ---------------------------------------------------------------------------
#define SCALE_LOG2E 0.18033688011112042f   // 0.125 * log2(e)

__global__ __launch_bounds__(256, 3) void attn_kernel(const unsigned short* __restrict__ qkv,
                                                      unsigned short* __restrict__ yb) {
    const int slot = blockIdx.y * 8 + blockIdx.x;
    const int logical = (slot & 7) * 96 + (slot >> 3);
    const int p = logical & 7;
    const int bh = logical >> 3;
    const int b = bh / NHEAD, h = bh % NHEAD;
    const int t = threadIdx.x, lane = t & 63, wid = t >> 6;
    const int q0A = p * 64 + wid * 16, q0B = (15 - p) * 64 + wid * 16;
    const int ntA = p + 1, ntB = 16 - p;          // ntA < ntB always
    const int ntT = (ntB + 1) >> 1;               // 128-row staging steps
    const int rrow = lane & 15, g = lane >> 4, kg8 = g * 8;

    __shared__ __attribute__((aligned(16))) unsigned short Ks[128 * 64];   // [kv][d]
    __shared__ __attribute__((aligned(16))) unsigned short Vt[64 * 152];   // [d][kv+pad]
    __shared__ __attribute__((aligned(16))) unsigned short Ps[4][16 * 80];

    bf16x8 qfA[2], qfB[2];
    {
        size_t baseA = ((size_t)(b * SEQ + q0A + rrow)) * 2304 + h * HS;
        qfA[0] = ld8(&qkv[baseA + kg8]);
        qfA[1] = ld8(&qkv[baseA + 32 + kg8]);
        size_t baseB = ((size_t)(b * SEQ + q0B + rrow)) * 2304 + h * HS;
        qfB[0] = ld8(&qkv[baseB + kg8]);
        qfB[1] = ld8(&qkv[baseB + 32 + kg8]);
    }

    f32x4 yA[4] = {}, yB[4] = {};
    float lA[4] = {0.f, 0.f, 0.f, 0.f}, lB[4] = {0.f, 0.f, 0.f, 0.f};

    const int kr = t >> 3;
    const int kc = ((t & 7) ^ (kr & 7)) * 8;
    const int vd = t & 63, vk = (t >> 6) * 32;

    unsigned short* P = &Ps[wid][0];
    const bf16x8 vones = __builtin_bit_cast(bf16x8,
        (ushort8){0x3F80, 0x3F80, 0x3F80, 0x3F80, 0x3F80, 0x3F80, 0x3F80, 0x3F80});
    const int sw = (rrow & 7) << 3;

    for (int tt = 0; tt < ntT; tt++) {
        const int kv0 = tt * 128;
        __syncthreads();   // previous tile's LDS reads complete
#pragma unroll
        for (int i = 0; i < 4; i++)
            glds16(&qkv[((size_t)(b * SEQ + kv0 + i * 32 + kr)) * 2304 + 768 + h * HS + kc],
                   &Ks[i * 2048 + wid * 512]);
#pragma unroll
        for (int iv = 0; iv < 4; iv++) {
            ushort8 v8;
#pragma unroll
            for (int i = 0; i < 8; i++)
                v8[i] = qkv[((size_t)(b * SEQ + kv0 + vk + iv * 8 + i)) * 2304 + 1536 + h * HS + vd];
            *(ushort8*)&Vt[vd * 152 + vk + iv * 8] = v8;
        }
        __syncthreads();   // staging visible (drains vmcnt + lgkmcnt)

#pragma unroll
        for (int hh = 0; hh < 2; hh++) {
            const int sidx = tt * 2 + hh;
            if (sidx >= ntB) continue;            // block-uniform
            const bool doA = (sidx < ntA);
            const bool maskB = (sidx == ntB - 1), maskA = (sidx == ntA - 1);
            const int kvs = kv0 + hh * 64;

            f32x4 sB[4], sA[4];
#pragma unroll
            for (int ct = 0; ct < 4; ct++) {
                const int j = ct * 16 + rrow;
                const unsigned short* krow = &Ks[(hh * 64 + j) * 64];
                bf16x8 k0 = ld8(&krow[((g    ) ^ (j & 7)) * 8]);
                bf16x8 k1 = ld8(&krow[((g + 4) ^ (j & 7)) * 8]);
                f32x4 zB = {};
                zB = mfma16x16x32(qfB[0], k0, zB);
                zB = mfma16x16x32(qfB[1], k1, zB);
                sB[ct] = zB;
                if (doA) {
                    f32x4 zA = {};
                    zA = mfma16x16x32(qfA[0], k0, zA);
                    zA = mfma16x16x32(qfA[1], k1, zA);
                    sA[ct] = zA;
                }
            }

            const int qrbB = q0B + g * 4;
#pragma unroll
            for (int ct = 0; ct < 4; ct++) {
                const int j = ct * 16 + rrow, jj = kvs + j;
#pragma unroll
                for (int r = 0; r < 4; r++) {
                    float v = sB[ct][r] * SCALE_LOG2E;
                    if (maskB && jj > qrbB + r) v = -1e30f;
                    const int q = g * 4 + r;
                    P[q * 80 + (j ^ ((q & 7) << 3))] = f2bf(exp2_fast(v));
                }
            }
            asm volatile("s_waitcnt lgkmcnt(0)" ::: "memory");
            __builtin_amdgcn_sched_barrier(0);
            {
                bf16x8 pa0 = ld8(&P[rrow * 80 + ((kg8     ) ^ sw)]);
                bf16x8 pa1 = ld8(&P[rrow * 80 + ((kg8 + 32) ^ sw)]);
                __builtin_amdgcn_s_setprio(1);
                f32x4 ss = {};
                ss = mfma16x16x32(pa0, vones, ss);
                ss = mfma16x16x32(pa1, vones, ss);
#pragma unroll
                for (int r = 0; r < 4; r++) lB[r] += ss[r];
#pragma unroll
                for (int dt = 0; dt < 4; dt++) {
                    const unsigned short* vr = &Vt[(dt * 16 + rrow) * 152 + hh * 64];
                    yB[dt] = mfma16x16x32(pa0, ld8(&vr[kg8     ]), yB[dt]);
                    yB[dt] = mfma16x16x32(pa1, ld8(&vr[kg8 + 32]), yB[dt]);
                }
                __builtin_amdgcn_s_setprio(0);
            }

            if (doA) {
                const int qrbA = q0A + g * 4;
#pragma unroll
                for (int ct = 0; ct < 4; ct++) {
                    const int j = ct * 16 + rrow, jj = kvs + j;
#pragma unroll
                    for (int r = 0; r < 4; r++) {
                        float v = sA[ct][r] * SCALE_LOG2E;
                        if (maskA && jj > qrbA + r) v = -1e30f;
                        const int q = g * 4 + r;
                        P[q * 80 + (j ^ ((q & 7) << 3))] = f2bf(exp2_fast(v));
                    }
                }
                asm volatile("s_waitcnt lgkmcnt(0)" ::: "memory");
                __builtin_amdgcn_sched_barrier(0);
                bf16x8 pa0 = ld8(&P[rrow * 80 + ((kg8     ) ^ sw)]);
                bf16x8 pa1 = ld8(&P[rrow * 80 + ((kg8 + 32) ^ sw)]);
                __builtin_amdgcn_s_setprio(1);
                f32x4 ss = {};
                ss = mfma16x16x32(pa0, vones, ss);
                ss = mfma16x16x32(pa1, vones, ss);
#pragma unroll
                for (int r = 0; r < 4; r++) lA[r] += ss[r];
#pragma unroll
                for (int dt = 0; dt < 4; dt++) {
                    const unsigned short* vr = &Vt[(dt * 16 + rrow) * 152 + hh * 64];
                    yA[dt] = mfma16x16x32(pa0, ld8(&vr[kg8     ]), yA[dt]);
                    yA[dt] = mfma16x16x32(pa1, ld8(&vr[kg8 + 32]), yA[dt]);
                }
                __builtin_amdgcn_s_setprio(0);
            }
        }
    }

#pragma unroll
    for (int dt = 0; dt < 4; dt++)
#pragma unroll
        for (int r = 0; r < 4; r++) {
            int col = h * HS + dt * 16 + rrow;
            yb[((size_t)(b * SEQ + q0B + g * 4 + r)) * N_EMBD + col] = f2bf(yB[dt][r] / lB[r]);
            yb[((size_t)(b * SEQ + q0A + g * 4 + r)) * N_EMBD + col] = f2bf(yA[dt][r] / lA[r]);
        }
}

// ---------------------------------------------------------------------------
// Orchestration
// ---------------------------------------------------------------------------
extern "C" void kernel_launch(void* const* d_in, const int* in_sizes, int n_in,
                              void* d_out, int out_size, void* d_ws, size_t ws_size,
                              hipStream_t stream) {
    const float* x        = (const float*)d_in[0];
    const float* ln1_g    = (const float*)d_in[1];
    const float* ln1_b    = (const float*)d_in[2];
    const float* w_attn   = (const float*)d_in[3];
    const float* b_attn   = (const float*)d_in[4];
    const float* w_proj   = (const float*)d_in[5];
    const float* b_proj   = (const float*)d_in[6];
    const float* ln2_g    = (const float*)d_in[7];
    const float* ln2_b    = (const float*)d_in[8];
    const float* w_fc     = (const float*)d_in[9];
    const float* b_fc     = (const float*)d_in[10];
    const float* w_fcp    = (const float*)d_in[11];
    const float* b_fcp    = (const float*)d_in[12];
    float* out = (float*)d_out;

    // workspace carve (ushort elements)
    unsigned short* ws = (unsigned short*)d_ws;
    unsigned short* wT_attn = ws;                          // 2304*768
    unsigned short* wT_proj = wT_attn + 2304 * 768;        // 768*768
    unsigned short* wT_fc   = wT_proj + 768 * 768;         // 3072*768
    unsigned short* wT_fcp  = wT_fc   + 3072 * 768;        // 768*3072
    unsigned short* xb      = wT_fcp  + 768 * 3072;        // 8192*768
    unsigned short* qkv     = xb      + (size_t)MROWS * 768;   // 8192*2304
    unsigned short* yb      = qkv     + (size_t)MROWS * 2304;  // 8192*768
    unsigned short* act     = qkv;    // 8192*3072 overlays qkv+yb (dead then)
    float* x2 = (float*)(yb + (size_t)MROWS * 768);        // 8192*768 fp32

    dim3 tb(32, 8);
    tcast_kernel<<<dim3(2304 / 32, 768 / 32), tb, 0, stream>>>(w_attn, wT_attn, 768, 2304);
    tcast_kernel<<<dim3(768 / 32, 768 / 32),  tb, 0, stream>>>(w_proj, wT_proj, 768, 768);
    tcast_kernel<<<dim3(3072 / 32, 768 / 32), tb, 0, stream>>>(w_fc,   wT_fc,   768, 3072);
    tcast_kernel<<<dim3(768 / 32, 3072 / 32), tb, 0, stream>>>(w_fcp,  wT_fcp,  3072, 768);

    // ln1 (wave-per-row)
    ln_kernel<<<MROWS / 4, 256, 0, stream>>>(x, ln1_g, ln1_b, xb);
    // qkv = ln1(x) @ w_attn + b_attn
    gemm_bt_kernel<0, 4><<<dim3(2304 / 128, MROWS / 128), 256, 0, stream>>>(
        xb, wT_attn, b_attn, nullptr, nullptr, qkv, MROWS, 2304, 768);
    // attention (paired q-tiles, KVBLK=128 staging)
    attn_kernel<<<dim3(8, 96), 256, 0, stream>>>(qkv, yb);
    // x2 = attn_y @ w_proj + b_proj + x
    gemm_bt_kernel<2, 2><<<dim3(768 / 128, MROWS / 64), 256, 0, stream>>>(
        yb, wT_proj, b_proj, x, x2, nullptr, MROWS, 768, 768);
    // ln2 (wave-per-row)
    ln_kernel<<<MROWS / 4, 256, 0, stream>>>(x2, ln2_g, ln2_b, xb);
    // act = gelu(h2 @ w_fc + b_fc)
    gemm_bt_kernel<1, 4><<<dim3(3072 / 128, MROWS / 128), 256, 0, stream>>>(
        xb, wT_fc, b_fc, nullptr, nullptr, act, MROWS, 3072, 768);
    // out = act @ w_fc_proj + b_fc_proj + x2
    gemm_bt_kernel<2, 2><<<dim3(768 / 128, MROWS / 64), 256, 0, stream>>>(
        act, wT_fcp, b_fcp, x2, out, nullptr, MROWS, 768, 3072);
}